// Round 1
// baseline (671.879 us; speedup 1.0000x reference)
//
#include <hip/hip_runtime.h>

// HyperbolicGraphPooling: out[g, :] = sum_{i : batch[i]==g} features[i,:] * sigmoid(features[i,:] @ W_att + b)
// N = 500000 nodes, C = 256 channels, 2048 graphs, batch sorted ascending.
//
// Fused single-pass: one wave per 64-node contiguous chunk. Lane l owns
// channels [4l, 4l+4) as a float4 (wave covers the full 1KB row coalesced).
// Dot via 6-step shfl_xor butterfly; local register accumulation while the
// segment id is unchanged (batch is sorted), atomicAdd flush on boundary.

constexpr int kChannels     = 256;
constexpr int kNodesPerWave = 64;

__global__ void hgp_fused_kernel(const float* __restrict__ features,
                                 const int*   __restrict__ batch,
                                 const float* __restrict__ W_att,
                                 const float* __restrict__ b_att,
                                 float*       __restrict__ out,
                                 int n_nodes) {
    const int gtid = blockIdx.x * blockDim.x + threadIdx.x;
    const int wave = gtid >> 6;
    const int lane = threadIdx.x & 63;

    const int start = wave * kNodesPerWave;
    if (start >= n_nodes) return;
    const int end = min(start + kNodesPerWave, n_nodes);

    // Per-lane fragment of the attention vector + bias (broadcast loads).
    const float4 w4  = reinterpret_cast<const float4*>(W_att)[lane];
    const float bias = b_att[0];

    const float4* __restrict__ frow = reinterpret_cast<const float4*>(features);

    float4 acc = make_float4(0.f, 0.f, 0.f, 0.f);
    int cur_seg = batch[start];

    // Software pipeline: cur row/seg in regs, prefetch next each iteration.
    float4 cur = frow[(size_t)start * (kChannels / 4) + lane];
    int seg = cur_seg;

    for (int n = start; n < end; ++n) {
        float4 nxt  = make_float4(0.f, 0.f, 0.f, 0.f);
        int    nseg = cur_seg;
        if (n + 1 < end) {
            nxt  = frow[(size_t)(n + 1) * (kChannels / 4) + lane];
            nseg = batch[n + 1];
        }

        // Segment boundary: flush the accumulated previous segment.
        if (seg != cur_seg) {
            float* o = out + (size_t)cur_seg * kChannels + lane * 4;
            atomicAdd(o + 0, acc.x);
            atomicAdd(o + 1, acc.y);
            atomicAdd(o + 2, acc.z);
            atomicAdd(o + 3, acc.w);
            acc = make_float4(0.f, 0.f, 0.f, 0.f);
            cur_seg = seg;
        }

        // Per-lane partial dot, then 64-lane butterfly reduce (all lanes get sum).
        float p = cur.x * w4.x + cur.y * w4.y + cur.z * w4.z + cur.w * w4.w;
        #pragma unroll
        for (int off = 32; off > 0; off >>= 1) p += __shfl_xor(p, off, 64);

        const float wgt = 1.0f / (1.0f + __expf(-(p + bias)));

        acc.x += cur.x * wgt;
        acc.y += cur.y * wgt;
        acc.z += cur.z * wgt;
        acc.w += cur.w * wgt;

        cur = nxt;
        seg = nseg;
    }

    // Final flush.
    float* o = out + (size_t)cur_seg * kChannels + lane * 4;
    atomicAdd(o + 0, acc.x);
    atomicAdd(o + 1, acc.y);
    atomicAdd(o + 2, acc.z);
    atomicAdd(o + 3, acc.w);
}

extern "C" void kernel_launch(void* const* d_in, const int* in_sizes, int n_in,
                              void* d_out, int out_size, void* d_ws, size_t ws_size,
                              hipStream_t stream) {
    const float* features = (const float*)d_in[0];
    const int*   batch    = (const int*)d_in[1];
    const float* W_att    = (const float*)d_in[2];
    const float* b_att    = (const float*)d_in[3];
    float*       out      = (float*)d_out;

    const int n_nodes = in_sizes[1];  // batch has one entry per node

    // Harness poisons d_out with 0xAA before every timed launch; we accumulate
    // with atomics, so zero it first (memset node is graph-capture legal).
    hipMemsetAsync(d_out, 0, (size_t)out_size * sizeof(float), stream);

    const int num_waves       = (n_nodes + kNodesPerWave - 1) / kNodesPerWave;
    const int waves_per_block = 4;  // 256 threads
    const int blocks          = (num_waves + waves_per_block - 1) / waves_per_block;

    hgp_fused_kernel<<<blocks, 256, 0, stream>>>(features, batch, W_att, b_att, out, n_nodes);
}

// Round 2
// 659.905 us; speedup vs baseline: 1.0181x; 1.0181x over previous
//
#include <hip/hip_runtime.h>

// HyperbolicGraphPooling: out[g, :] = sum_{i : batch[i]==g} features[i,:] * sigmoid(features[i,:] @ W_att + b)
// N = 500000 nodes, C = 256 channels, 2048 graphs, batch sorted ascending.
//
// One wave per 64-node contiguous chunk. Lane l owns channels [4l, 4l+4) as a
// float4 (wave covers the full 1KB row, coalesced dwordx4). 4-way unrolled:
// 4 row loads in flight, 4 independent shfl_xor butterfly reductions
// interleaved for ILP (the R1 version's dependent 6-step chain per node was
// the latency bottleneck). Register accumulation while segment id unchanged
// (batch sorted); atomicAdd flush on boundary (~1.26 flushes/wave avg).

constexpr int kChannels     = 256;
constexpr int kNodesPerWave = 64;
constexpr int kVecPerRow    = kChannels / 4;  // 64 float4 per row

__global__ void hgp_fused_kernel(const float* __restrict__ features,
                                 const int*   __restrict__ batch,
                                 const float* __restrict__ W_att,
                                 const float* __restrict__ b_att,
                                 float*       __restrict__ out,
                                 int n_nodes) {
    const int gtid = blockIdx.x * blockDim.x + threadIdx.x;
    const int wave = gtid >> 6;
    const int lane = threadIdx.x & 63;

    const int start = wave * kNodesPerWave;
    if (start >= n_nodes) return;
    const int end = min(start + kNodesPerWave, n_nodes);

    const float4 w4  = reinterpret_cast<const float4*>(W_att)[lane];
    const float bias = b_att[0];
    const float4* __restrict__ frow = reinterpret_cast<const float4*>(features);

    float4 acc = make_float4(0.f, 0.f, 0.f, 0.f);
    int cur_seg = batch[start];

    auto flush = [&](int segid, const float4& v) {
        float* o = out + (size_t)segid * kChannels + lane * 4;
        atomicAdd(o + 0, v.x);
        atomicAdd(o + 1, v.y);
        atomicAdd(o + 2, v.z);
        atomicAdd(o + 3, v.w);
    };

    int n = start;
    for (; n + 4 <= end; n += 4) {
        const size_t base = (size_t)n * kVecPerRow + lane;
        float4 r0 = frow[base];
        float4 r1 = frow[base + 1 * kVecPerRow];
        float4 r2 = frow[base + 2 * kVecPerRow];
        float4 r3 = frow[base + 3 * kVecPerRow];
        const int s0 = batch[n + 0];
        const int s1 = batch[n + 1];
        const int s2 = batch[n + 2];
        const int s3 = batch[n + 3];

        float p0 = r0.x * w4.x + r0.y * w4.y + r0.z * w4.z + r0.w * w4.w;
        float p1 = r1.x * w4.x + r1.y * w4.y + r1.z * w4.z + r1.w * w4.w;
        float p2 = r2.x * w4.x + r2.y * w4.y + r2.z * w4.z + r2.w * w4.w;
        float p3 = r3.x * w4.x + r3.y * w4.y + r3.z * w4.z + r3.w * w4.w;

        // 4 independent butterfly chains interleaved -> 4-way ILP on the
        // cross-lane pipe instead of one serial 6-deep chain per node.
        #pragma unroll
        for (int off = 32; off > 0; off >>= 1) {
            p0 += __shfl_xor(p0, off, 64);
            p1 += __shfl_xor(p1, off, 64);
            p2 += __shfl_xor(p2, off, 64);
            p3 += __shfl_xor(p3, off, 64);
        }

        const float g0 = 1.0f / (1.0f + __expf(-(p0 + bias)));
        const float g1 = 1.0f / (1.0f + __expf(-(p1 + bias)));
        const float g2 = 1.0f / (1.0f + __expf(-(p2 + bias)));
        const float g3 = 1.0f / (1.0f + __expf(-(p3 + bias)));

        if (s0 != cur_seg) { flush(cur_seg, acc); acc = make_float4(0.f,0.f,0.f,0.f); cur_seg = s0; }
        acc.x += r0.x * g0; acc.y += r0.y * g0; acc.z += r0.z * g0; acc.w += r0.w * g0;

        if (s1 != cur_seg) { flush(cur_seg, acc); acc = make_float4(0.f,0.f,0.f,0.f); cur_seg = s1; }
        acc.x += r1.x * g1; acc.y += r1.y * g1; acc.z += r1.z * g1; acc.w += r1.w * g1;

        if (s2 != cur_seg) { flush(cur_seg, acc); acc = make_float4(0.f,0.f,0.f,0.f); cur_seg = s2; }
        acc.x += r2.x * g2; acc.y += r2.y * g2; acc.z += r2.z * g2; acc.w += r2.w * g2;

        if (s3 != cur_seg) { flush(cur_seg, acc); acc = make_float4(0.f,0.f,0.f,0.f); cur_seg = s3; }
        acc.x += r3.x * g3; acc.y += r3.y * g3; acc.z += r3.z * g3; acc.w += r3.w * g3;
    }

    // Tail (last wave has 32 nodes: 500000 = 7812*64 + 32; still multiple of 4,
    // but keep a scalar tail for generality).
    for (; n < end; ++n) {
        float4 r = frow[(size_t)n * kVecPerRow + lane];
        const int s = batch[n];

        float p = r.x * w4.x + r.y * w4.y + r.z * w4.z + r.w * w4.w;
        #pragma unroll
        for (int off = 32; off > 0; off >>= 1) p += __shfl_xor(p, off, 64);
        const float g = 1.0f / (1.0f + __expf(-(p + bias)));

        if (s != cur_seg) { flush(cur_seg, acc); acc = make_float4(0.f,0.f,0.f,0.f); cur_seg = s; }
        acc.x += r.x * g; acc.y += r.y * g; acc.z += r.z * g; acc.w += r.w * g;
    }

    flush(cur_seg, acc);
}

extern "C" void kernel_launch(void* const* d_in, const int* in_sizes, int n_in,
                              void* d_out, int out_size, void* d_ws, size_t ws_size,
                              hipStream_t stream) {
    const float* features = (const float*)d_in[0];
    const int*   batch    = (const int*)d_in[1];
    const float* W_att    = (const float*)d_in[2];
    const float* b_att    = (const float*)d_in[3];
    float*       out      = (float*)d_out;

    const int n_nodes = in_sizes[1];  // batch has one entry per node

    // Harness poisons d_out with 0xAA; we accumulate with atomics, so zero it
    // (memset node is graph-capture legal). 2 MB -> ~1 us.
    hipMemsetAsync(d_out, 0, (size_t)out_size * sizeof(float), stream);

    const int num_waves       = (n_nodes + kNodesPerWave - 1) / kNodesPerWave;
    const int waves_per_block = 4;  // 256 threads
    const int blocks          = (num_waves + waves_per_block - 1) / waves_per_block;

    hgp_fused_kernel<<<blocks, 256, 0, stream>>>(features, batch, W_att, b_att, out, n_nodes);
}

// Round 3
// 625.907 us; speedup vs baseline: 1.0734x; 1.0543x over previous
//
#include <hip/hip_runtime.h>

// HyperbolicGraphPooling: out[g,:] = sum_{i: batch[i]==g} f[i,:] * sigmoid(f[i,:]@W + b)
// N=500000, C=256, G=2048, batch sorted ascending.
//
// R3: deterministic segment-per-block decomposition (no atomics, no memset).
// Block g binary-searches its node range in the sorted batch array, its 4
// waves each stream a contiguous quarter (lane l owns channels [4l,4l+4) as
// float4 -> each load instr is one full coalesced 1KB row), 4-way unrolled
// with interleaved 6-step shfl_xor butterflies for the attention dot, then an
// LDS cross-wave reduce and a single plain store of out[g,:]. Grid = 2048
// blocks = exactly 8 blocks/CU. Non-temporal feature loads (read-once stream).

constexpr int kChannels  = 256;
constexpr int kVecPerRow = kChannels / 4;  // 64 float4 per row

typedef float vfloat4 __attribute__((ext_vector_type(4)));

__device__ inline int lower_bound_i32(const int* __restrict__ b, int n, int v) {
    int lo = 0, hi = n;
    while (lo < hi) {
        int mid = (lo + hi) >> 1;
        if (b[mid] < v) lo = mid + 1; else hi = mid;
    }
    return lo;
}

__device__ inline float sigmoidf(float x) {
    return 1.0f / (1.0f + __expf(-x));
}

__global__ void hgp_seg_kernel(const float* __restrict__ features,
                               const int*   __restrict__ batch,
                               const float* __restrict__ W_att,
                               const float* __restrict__ b_att,
                               float*       __restrict__ out,
                               int n_nodes) {
    const int g    = blockIdx.x;          // segment id
    const int wv   = threadIdx.x >> 6;    // wave 0..3
    const int lane = threadIdx.x & 63;

    // Segment bounds (uniform across block; scalar-friendly binary search).
    const int seg_start = lower_bound_i32(batch, n_nodes, g);
    const int seg_end   = lower_bound_i32(batch, n_nodes, g + 1);
    const int seg_len   = seg_end - seg_start;

    // Wave's contiguous quarter of the segment.
    const int q   = (seg_len + 3) >> 2;
    const int ws_ = seg_start + wv * q;
    const int we_ = min(ws_ + q, seg_end);

    const float4 w4  = reinterpret_cast<const float4*>(W_att)[lane];
    const float bias = b_att[0];
    const vfloat4* __restrict__ frow = reinterpret_cast<const vfloat4*>(features);

    float ax = 0.f, ay = 0.f, az = 0.f, aw = 0.f;

    int n = ws_;
    for (; n + 4 <= we_; n += 4) {
        const size_t base = (size_t)n * kVecPerRow + lane;
        vfloat4 r0 = __builtin_nontemporal_load(&frow[base]);
        vfloat4 r1 = __builtin_nontemporal_load(&frow[base + 1 * kVecPerRow]);
        vfloat4 r2 = __builtin_nontemporal_load(&frow[base + 2 * kVecPerRow]);
        vfloat4 r3 = __builtin_nontemporal_load(&frow[base + 3 * kVecPerRow]);

        float p0 = r0[0] * w4.x + r0[1] * w4.y + r0[2] * w4.z + r0[3] * w4.w;
        float p1 = r1[0] * w4.x + r1[1] * w4.y + r1[2] * w4.z + r1[3] * w4.w;
        float p2 = r2[0] * w4.x + r2[1] * w4.y + r2[2] * w4.z + r2[3] * w4.w;
        float p3 = r3[0] * w4.x + r3[1] * w4.y + r3[2] * w4.z + r3[3] * w4.w;

        #pragma unroll
        for (int off = 32; off > 0; off >>= 1) {
            p0 += __shfl_xor(p0, off, 64);
            p1 += __shfl_xor(p1, off, 64);
            p2 += __shfl_xor(p2, off, 64);
            p3 += __shfl_xor(p3, off, 64);
        }

        const float g0 = sigmoidf(p0 + bias);
        const float g1 = sigmoidf(p1 + bias);
        const float g2 = sigmoidf(p2 + bias);
        const float g3 = sigmoidf(p3 + bias);

        ax += r0[0] * g0 + r1[0] * g1 + r2[0] * g2 + r3[0] * g3;
        ay += r0[1] * g0 + r1[1] * g1 + r2[1] * g2 + r3[1] * g3;
        az += r0[2] * g0 + r1[2] * g1 + r2[2] * g2 + r3[2] * g3;
        aw += r0[3] * g0 + r1[3] * g1 + r2[3] * g2 + r3[3] * g3;
    }
    for (; n < we_; ++n) {
        vfloat4 r = __builtin_nontemporal_load(&frow[(size_t)n * kVecPerRow + lane]);
        float p = r[0] * w4.x + r[1] * w4.y + r[2] * w4.z + r[3] * w4.w;
        #pragma unroll
        for (int off = 32; off > 0; off >>= 1) p += __shfl_xor(p, off, 64);
        const float gg = sigmoidf(p + bias);
        ax += r[0] * gg; ay += r[1] * gg; az += r[2] * gg; aw += r[3] * gg;
    }

    // Cross-wave reduce in LDS, then one plain coalesced store of out[g,:].
    __shared__ float lds[4][kChannels];
    lds[wv][lane * 4 + 0] = ax;
    lds[wv][lane * 4 + 1] = ay;
    lds[wv][lane * 4 + 2] = az;
    lds[wv][lane * 4 + 3] = aw;
    __syncthreads();

    const int t = threadIdx.x;  // 0..255 == channel
    const float s = lds[0][t] + lds[1][t] + lds[2][t] + lds[3][t];
    out[(size_t)g * kChannels + t] = s;
}

extern "C" void kernel_launch(void* const* d_in, const int* in_sizes, int n_in,
                              void* d_out, int out_size, void* d_ws, size_t ws_size,
                              hipStream_t stream) {
    const float* features = (const float*)d_in[0];
    const int*   batch    = (const int*)d_in[1];
    const float* W_att    = (const float*)d_in[2];
    const float* b_att    = (const float*)d_in[3];
    float*       out      = (float*)d_out;

    const int n_nodes    = in_sizes[1];          // one batch entry per node
    const int num_graphs = out_size / kChannels; // 2048

    // Every out element is written unconditionally (empty segments write 0),
    // so no memset needed despite the 0xAA poison.
    hgp_seg_kernel<<<num_graphs, 256, 0, stream>>>(features, batch, W_att, b_att,
                                                   out, n_nodes);
}